// Round 5
// baseline (438.841 us; speedup 1.0000x reference)
//
#include <hip/hip_runtime.h>

// z: [16,4096,256] fp32 -> N=65536 rows, d=256
// embedding: [256,1024], cluster_size: [1024], embedding_mean: [256,1024]

#define DECAYC 0.99f
#define EPSQ 1e-5f

typedef unsigned short ushort_t;
typedef __attribute__((ext_vector_type(8))) short bf16x8;
typedef __attribute__((ext_vector_type(4))) float f32x4;
typedef unsigned long long u64;

__device__ __forceinline__ ushort_t f2bf(float x) {
    unsigned u = __float_as_uint(x);
    unsigned r = (u + 0x7FFFu + ((u >> 16) & 1u)) >> 16;   // RNE
    return (ushort_t)r;
}
__device__ __forceinline__ float bf2f(ushort_t h) {
    return __uint_as_float(((unsigned)h) << 16);
}
__device__ __forceinline__ u64 umin64(u64 a, u64 b) { return a < b ? a : b; }

// ---------------- E-side prep (fused): ET + colnorm + Eph/Epl + zero stats ----------------
__global__ __launch_bounds__(256) void prep_E_kernel(const float* __restrict__ E,
                                                     float* __restrict__ ET,
                                                     float* __restrict__ colnorm,
                                                     ushort_t* __restrict__ Eph,
                                                     ushort_t* __restrict__ Epl,
                                                     int* __restrict__ counts,
                                                     float* __restrict__ lossSum) {
    int n = blockIdx.x;
    int d = threadIdx.x;
    if (d == 0) counts[n] = 0;
    if (n == 0 && d == 1) lossSum[0] = 0.f;
    float v = E[d * 1024 + n];
    ET[n * 256 + d] = v;
    ushort_t h = f2bf(v);
    ushort_t l = f2bf(v - bf2f(h));
    size_t pi = ((size_t)(d >> 3) * 1024 + n) * 8 + (d & 7);
    Eph[pi] = h;
    Epl[pi] = l;
    __shared__ float red[256];
    red[d] = v * v;
    __syncthreads();
    for (int o = 128; o > 0; o >>= 1) {
        if (d < o) red[d] += red[d + o];
        __syncthreads();
    }
    if (d == 0) colnorm[n] = red[0];
}

// ---------------- MFMA distance + argmin + fused gather/loss/hist ----------------
// Round-12: round-4 structure + ILP fix. Round-4 post-mortem: occupancy is
// register-bound at 2 waves/SIMD (128 VGPR + 32 AGPR acc -> 129-256 bucket)
// regardless of LDS; the (256,2) 128-reg cap prevented the compiler from
// double-buffering the 8 B-fragment loads per ks (32 regs/stage) -> serialized
// load->MFMA = ~30% MfmaUtil. Fix: __launch_bounds__(256,1) (cap 256; can't
// lose occupancy, already at 2/SIMD floor) + EXPLICIT B double-buffer: issue
// ks+1's 8 global loads before ks's 24 MFMAs. Live state ~147 regs.
__global__ __launch_bounds__(256, 1) void dist_mfma_kernel(const float* __restrict__ z,
                                                           const ushort_t* __restrict__ Eph,
                                                           const ushort_t* __restrict__ Epl,
                                                           const float* __restrict__ colnorm,
                                                           const float* __restrict__ ET,
                                                           float* __restrict__ out0,
                                                           float* __restrict__ lossSum,
                                                           int* __restrict__ counts,
                                                           int* __restrict__ idxOut) {
    __shared__ __align__(16) ushort_t Ah[8192];    // slots (kq*32+r)*8, 16 KB
    __shared__ __align__(16) ushort_t Al[8192];
    __shared__ u64 bl[4][32];                      // per-wave row minima
    __shared__ float zpart[8][32];                 // ||z||^2 partials
    __shared__ int kArr[32];

    const int t = threadIdx.x;
    const int lane = t & 63;
    const int w = t >> 6;          // wave 0..3 (code group: codes w*64 within 256-chunk)
    const int n16 = lane & 15;
    const int q = lane >> 4;       // 0..3
    const int rowBase = blockIdx.x * 32;

    // ---- one-time: convert 32 z rows to bf16 hi/lo in LDS + ||z||^2 partials ----
    float zsq = 0.f;
#pragma unroll
    for (int i = 0; i < 4; ++i) {
        int s = i * 256 + t;       // 0..1023 : kq = s>>5, r = s&31 (== t&31, const/thread)
        const float* gp = z + (size_t)(rowBase + (s & 31)) * 256 + (s >> 5) * 8;
        float4 v0 = *(const float4*)gp;
        float4 v1 = *(const float4*)(gp + 4);
        float vv[8] = {v0.x, v0.y, v0.z, v0.w, v1.x, v1.y, v1.z, v1.w};
        ushort_t hh[8], ll[8];
#pragma unroll
        for (int j = 0; j < 8; ++j) {
            hh[j] = f2bf(vv[j]);
            ll[j] = f2bf(vv[j] - bf2f(hh[j]));
            zsq += vv[j] * vv[j];
        }
        ushort4 h0 = {hh[0], hh[1], hh[2], hh[3]}, h1 = {hh[4], hh[5], hh[6], hh[7]};
        ushort4 l0 = {ll[0], ll[1], ll[2], ll[3]}, l1 = {ll[4], ll[5], ll[6], ll[7]};
        *(ushort4*)&Ah[s * 8] = h0;
        *(ushort4*)&Ah[s * 8 + 4] = h1;
        *(ushort4*)&Al[s * 8] = l0;
        *(ushort4*)&Al[s * 8 + 4] = l1;
    }
    zpart[t >> 5][t & 31] = zsq;
    __syncthreads();

    // argmin state: one sortable u32 per output element.
    // key = (sortable(dist) & ~15) | (cb<<2) | ct ; umin => min dist, tie -> lowest code.
    unsigned bestk[2][4];
#pragma unroll
    for (int rt = 0; rt < 2; ++rt)
#pragma unroll
        for (int reg = 0; reg < 4; ++reg) bestk[rt][reg] = 0xFFFFFFFFu;

    for (int cb = 0; cb < 4; ++cb) {
        const int cBase = cb * 256 + w * 64;
        f32x4 acc[2][4];
#pragma unroll
        for (int rt = 0; rt < 2; ++rt)
#pragma unroll
            for (int ct = 0; ct < 4; ++ct) acc[rt][ct] = (f32x4){0.f, 0.f, 0.f, 0.f};

        // B double-buffer: prologue loads ks=0
        bf16x8 bufh[2][4], bufl[2][4];
        {
            const size_t bb = ((size_t)q * 1024 + cBase + n16) * 8;
#pragma unroll
            for (int ct = 0; ct < 4; ++ct) {
                bufh[0][ct] = *(const bf16x8*)(Eph + bb + ct * 128);
                bufl[0][ct] = *(const bf16x8*)(Epl + bb + ct * 128);
            }
        }

#pragma unroll
        for (int ks = 0; ks < 8; ++ks) {
            const int cur = ks & 1;
            const int nxt = cur ^ 1;
            if (ks < 7) {
                const int kqn = (ks + 1) * 4 + q;
                const size_t bb = ((size_t)kqn * 1024 + cBase + n16) * 8;
#pragma unroll
                for (int ct = 0; ct < 4; ++ct) {
                    bufh[nxt][ct] = *(const bf16x8*)(Eph + bb + ct * 128);
                    bufl[nxt][ct] = *(const bf16x8*)(Epl + bb + ct * 128);
                }
            }
            const int kq = ks * 4 + q;                       // 0..31
            bf16x8 afh[2], afl[2];
#pragma unroll
            for (int rt = 0; rt < 2; ++rt) {
                int ao = (kq * 32 + rt * 16 + n16) * 8;
                afh[rt] = *(const bf16x8*)&Ah[ao];
                afl[rt] = *(const bf16x8*)&Al[ao];
            }
#pragma unroll
            for (int rt = 0; rt < 2; ++rt)
#pragma unroll
                for (int ct = 0; ct < 4; ++ct) {
                    acc[rt][ct] = __builtin_amdgcn_mfma_f32_16x16x32_bf16(afh[rt], bufh[cur][ct], acc[rt][ct], 0, 0, 0);
                    acc[rt][ct] = __builtin_amdgcn_mfma_f32_16x16x32_bf16(afh[rt], bufl[cur][ct], acc[rt][ct], 0, 0, 0);
                    acc[rt][ct] = __builtin_amdgcn_mfma_f32_16x16x32_bf16(afl[rt], bufh[cur][ct], acc[rt][ct], 0, 0, 0);
                }
        }

        // lane-local argmin update: dist = cn - 2*dot (+||z||^2 added at the end)
        float cn[4];
#pragma unroll
        for (int ct = 0; ct < 4; ++ct) cn[ct] = colnorm[cBase + ct * 16 + n16];
#pragma unroll
        for (int rt = 0; rt < 2; ++rt)
#pragma unroll
            for (int reg = 0; reg < 4; ++reg) {
                unsigned b = bestk[rt][reg];
#pragma unroll
                for (int ct = 0; ct < 4; ++ct) {
                    float dist = cn[ct] - 2.f * acc[rt][ct][reg];
                    unsigned fb = __float_as_uint(dist);
                    unsigned sk = (fb & 0x80000000u) ? ~fb : (fb | 0x80000000u);
                    unsigned key = (sk & 0xFFFFFFF0u) | ((unsigned)cb << 2) | (unsigned)ct;
                    b = key < b ? key : b;
                }
                bestk[rt][reg] = b;
            }
    }

    // one-time: expand key -> (dist|code) u64 + cross-lane min within 16-lane col group
#pragma unroll
    for (int rt = 0; rt < 2; ++rt)
#pragma unroll
        for (int reg = 0; reg < 4; ++reg) {
            unsigned key = bestk[rt][reg];
            unsigned cbct = key & 15u;
            unsigned code = (cbct >> 2) * 256u + (unsigned)(w * 64) + (cbct & 3u) * 16u + (unsigned)n16;
            u64 b = ((u64)(key & 0xFFFFFFF0u) << 32) | code;
            b = umin64(b, __shfl_xor(b, 1, 64));
            b = umin64(b, __shfl_xor(b, 2, 64));
            b = umin64(b, __shfl_xor(b, 4, 64));
            b = umin64(b, __shfl_xor(b, 8, 64));
            if (n16 == 0) bl[w][rt * 16 + q * 4 + reg] = b;
        }
    __syncthreads();

    // ---- epilogue: merge wave quarters, decode key -> code + loss, hist ----
    if (t < 32) {
        u64 b = umin64(umin64(bl[0][t], bl[1][t]), umin64(bl[2][t], bl[3][t]));
        int k = (int)(unsigned)(b & 0xFFFFFFFFull);
        unsigned sk = (unsigned)(b >> 32);
        unsigned fb = (sk & 0x80000000u) ? (sk ^ 0x80000000u) : ~sk;
        float zn = 0.f;
#pragma unroll
        for (int g = 0; g < 8; ++g) zn += zpart[g][t];
        float dmin = __uint_as_float(fb) + zn;
        idxOut[rowBase + t] = k;
        kArr[t] = k;
        atomicAdd(counts + k, 1);
        float v = dmin;
        v += __shfl_xor(v, 16, 64);
        v += __shfl_xor(v, 8, 64);
        v += __shfl_xor(v, 4, 64);
        v += __shfl_xor(v, 2, 64);
        v += __shfl_xor(v, 1, 64);
        if (t == 0) atomicAdd(lossSum, v);
    }
    __syncthreads();

    // ---- gather z_q: wave w writes rows w*8..w*8+7 (no z re-read) ----
#pragma unroll
    for (int i = 0; i < 8; ++i) {
        int r = w * 8 + i;
        int k = kArr[r];
        float4 qv = *(const float4*)(ET + (size_t)k * 256 + lane * 4);
        *(float4*)(out0 + (size_t)(rowBase + r) * 256 + lane * 4) = qv;
    }
}

// ---------------- cluster_size_new + n + loss finalize (no prefix/sort needed) ----------------
__global__ __launch_bounds__(1024) void csn_kernel(const int* __restrict__ counts,
                                                   const float* __restrict__ cluster_size,
                                                   const float* __restrict__ lossSum,
                                                   float* __restrict__ out3,
                                                   float* __restrict__ out1,
                                                   float* __restrict__ nOut) {
    int t = threadIdx.x;
    int c = counts[t];
    float cn = cluster_size[t] * DECAYC + (1.f - DECAYC) * (float)c;
    out3[t] = cn;
    float v = cn;
#pragma unroll
    for (int o = 32; o > 0; o >>= 1) v += __shfl_down(v, o, 64);
    __shared__ float fbuf[16];
    int lane = t & 63, wv = t >> 6;
    if (lane == 0) fbuf[wv] = v;
    __syncthreads();
    if (t == 0) {
        float n = 0.f;
#pragma unroll
        for (int i = 0; i < 16; ++i) n += fbuf[i];
        nOut[0] = n;
        out1[0] = 0.25f * lossSum[0] / 16777216.0f;
    }
}

// ---------------- fused segsum + embedding_mean_new + embedding_new ----------------
// Round-12: replaces scatter_sort (65K global-atomic burst over 64 cachelines)
// + segsum + final8. One block per code k: scan idx in 8 chunks of 8192 (LDS
// match-list, worst-case-safe), cooperatively sum matching z rows (coalesced
// 1KB row loads, thread t owns dim t), then write the k-th column of both
// embedding outputs directly.
__global__ __launch_bounds__(256) void segsum_final_kernel(const float* __restrict__ z,
                                                           const int* __restrict__ idx,
                                                           const float* __restrict__ embedding_mean,
                                                           const float* __restrict__ csn,
                                                           const float* __restrict__ nPtr,
                                                           float* __restrict__ out2,
                                                           float* __restrict__ out4) {
    const int k = blockIdx.x;
    const int t = threadIdx.x;
    __shared__ int list[8192];
    __shared__ int lcnt;
    float acc = 0.f;
    for (int ch = 0; ch < 8; ++ch) {
        if (t == 0) lcnt = 0;
        __syncthreads();
        const int base = ch * 8192;
#pragma unroll
        for (int i = 0; i < 32; ++i) {
            int j = base + i * 256 + t;
            if (idx[j] == k) {
                int p = atomicAdd(&lcnt, 1);
                list[p] = j;
            }
        }
        __syncthreads();
        const int m = lcnt;
        for (int li = 0; li < m; ++li) {
            int row = list[li];
            acc += z[(size_t)row * 256 + t];
        }
        __syncthreads();
    }
    float emn = embedding_mean[t * 1024 + k] * DECAYC + (1.f - DECAYC) * acc;
    out4[t * 1024 + k] = emn;
    float n = nPtr[0];
    float c = csn[k];
    float cs = (c + EPSQ) / (n + 1024.f * EPSQ) * n;
    out2[t * 1024 + k] = emn / cs;
}

extern "C" void kernel_launch(void* const* d_in, const int* in_sizes, int n_in,
                              void* d_out, int out_size, void* d_ws, size_t ws_size,
                              hipStream_t stream) {
    const float* z = (const float*)d_in[0];
    const float* E = (const float*)d_in[1];
    const float* cluster_size = (const float*)d_in[2];
    const float* embedding_mean = (const float*)d_in[3];

    float* out0 = (float*)d_out;        // z_q_st
    float* out1 = out0 + 16777216;      // vq_loss
    float* out2 = out1 + 1;             // embedding_new
    float* out3 = out2 + 262144;        // cluster_size_new
    float* out4 = out3 + 1024;          // embedding_mean_new

    // ws layout (float units)
    float* ws = (float*)d_ws;
    float* colnorm = ws;                         // 1024
    int* idx = (int*)(ws + 1024);                // 65536
    int* counts = (int*)(ws + 66560);            // 1024  (zeroed in prep_E)
    float* lossSum = ws + 67584;                 // 1     (zeroed in prep_E)
    float* nOut = ws + 67585;                    // 1
    float* ET = ws + 67588;                      // 262144 fp32 [k][d]
    ushort_t* Eph = (ushort_t*)(ws + 329732);    // 262144 ushort
    ushort_t* Epl = (ushort_t*)(ws + 460804);    // 262144 ushort

    prep_E_kernel<<<1024, 256, 0, stream>>>(E, ET, colnorm, Eph, Epl, counts, lossSum);
    dist_mfma_kernel<<<2048, 256, 0, stream>>>(z, Eph, Epl, colnorm, ET,
                                               out0, lossSum, counts, idx);
    csn_kernel<<<1, 1024, 0, stream>>>(counts, cluster_size, lossSum, out3, out1, nOut);
    segsum_final_kernel<<<1024, 256, 0, stream>>>(z, idx, embedding_mean, out3, nOut,
                                                  out2, out4);
}

// Round 6
// 422.258 us; speedup vs baseline: 1.0393x; 1.0393x over previous
//
#include <hip/hip_runtime.h>

// z: [16,4096,256] fp32 -> N=65536 rows, d=256
// embedding: [256,1024], cluster_size: [1024], embedding_mean: [256,1024]

#define DECAYC 0.99f
#define EPSQ 1e-5f

typedef unsigned short ushort_t;
typedef __attribute__((ext_vector_type(8))) short bf16x8;
typedef __attribute__((ext_vector_type(4))) float f32x4;
typedef unsigned long long u64;

__device__ __forceinline__ ushort_t f2bf(float x) {
    unsigned u = __float_as_uint(x);
    unsigned r = (u + 0x7FFFu + ((u >> 16) & 1u)) >> 16;   // RNE
    return (ushort_t)r;
}
__device__ __forceinline__ float bf2f(ushort_t h) {
    return __uint_as_float(((unsigned)h) << 16);
}
__device__ __forceinline__ u64 umin64(u64 a, u64 b) { return a < b ? a : b; }

// ---------------- E-side prep (fused): ET + colnorm + Eph/Epl + zero stats ----------------
__global__ __launch_bounds__(256) void prep_E_kernel(const float* __restrict__ E,
                                                     float* __restrict__ ET,
                                                     float* __restrict__ colnorm,
                                                     ushort_t* __restrict__ Eph,
                                                     ushort_t* __restrict__ Epl,
                                                     int* __restrict__ counts,
                                                     float* __restrict__ lossSum) {
    int n = blockIdx.x;
    int d = threadIdx.x;
    if (d == 0) counts[n] = 0;
    if (n == 0 && d == 1) lossSum[0] = 0.f;
    float v = E[d * 1024 + n];
    ET[n * 256 + d] = v;
    ushort_t h = f2bf(v);
    ushort_t l = f2bf(v - bf2f(h));
    size_t pi = ((size_t)(d >> 3) * 1024 + n) * 8 + (d & 7);
    Eph[pi] = h;
    Epl[pi] = l;
    __shared__ float red[256];
    red[d] = v * v;
    __syncthreads();
    for (int o = 128; o > 0; o >>= 1) {
        if (d < o) red[d] += red[d + o];
        __syncthreads();
    }
    if (d == 0) colnorm[n] = red[0];
}

// ---------------- MFMA distance + argmin + fused gather/loss/hist ----------------
// ROUND-0 VERBATIM (proven 142us, VGPR=128, no spill). Rounds 1-5 post-mortems:
// every attempt to beat this (32x32 shape, 4-wave occupancy, reg double-buffer)
// lost via the register/occupancy tradeoff: live state +X regs crosses a
// waves/SIMD boundary and costs more latency-hiding than the ILP it buys.
// Block: 64 rows x 1024 codes. 256 thr = 4 waves, 2x2 of (32 rows x 64 codes).
__global__ __launch_bounds__(256, 2) void dist_mfma_kernel(const float* __restrict__ z,
                                                           const ushort_t* __restrict__ Eph,
                                                           const ushort_t* __restrict__ Epl,
                                                           const float* __restrict__ colnorm,
                                                           const float* __restrict__ ET,
                                                           float* __restrict__ out0,
                                                           float* __restrict__ lossSum,
                                                           int* __restrict__ counts,
                                                           int* __restrict__ idxOut) {
    __shared__ __align__(16) ushort_t Ah[16384];   // slots (kq*64+r)*8, 32 KB
    __shared__ __align__(16) ushort_t Al[16384];
    __shared__ u64 bl[2][64];                      // per-wcol row minima
    __shared__ float zpart[4][64];                 // per-wave ||z||^2 partials
    __shared__ int kArr[64];
    __shared__ float sred[1];

    const int t = threadIdx.x;
    const int lane = t & 63;
    const int w = t >> 6;          // wave 0..3
    const int wrow = w >> 1;       // 0..1 (rows wrow*32..)
    const int wcol = w & 1;        // 0..1 (codes wcol*64.. within chunk)
    const int n16 = lane & 15;
    const int q = lane >> 4;       // 0..3
    const int rowBase = blockIdx.x * 64;

    // ---- one-time: convert 64 z rows to bf16 hi/lo in LDS + ||z||^2 partials ----
    float zsq = 0.f;
#pragma unroll
    for (int i = 0; i < 8; ++i) {
        int s = i * 256 + t;       // slot: kq = s>>6, r = s&63
        int kq = s >> 6;
        int r = s & 63;
        const float* gp = z + (size_t)(rowBase + r) * 256 + kq * 8;
        float4 v0 = *(const float4*)gp;
        float4 v1 = *(const float4*)(gp + 4);
        float vv[8] = {v0.x, v0.y, v0.z, v0.w, v1.x, v1.y, v1.z, v1.w};
        ushort_t hh[8], ll[8];
#pragma unroll
        for (int j = 0; j < 8; ++j) {
            hh[j] = f2bf(vv[j]);
            ll[j] = f2bf(vv[j] - bf2f(hh[j]));
            zsq += vv[j] * vv[j];
        }
        ushort4 h0 = {hh[0], hh[1], hh[2], hh[3]}, h1 = {hh[4], hh[5], hh[6], hh[7]};
        ushort4 l0 = {ll[0], ll[1], ll[2], ll[3]}, l1 = {ll[4], ll[5], ll[6], ll[7]};
        *(ushort4*)&Ah[s * 8] = h0;
        *(ushort4*)&Ah[s * 8 + 4] = h1;
        *(ushort4*)&Al[s * 8] = l0;
        *(ushort4*)&Al[s * 8 + 4] = l1;
    }
    zpart[w][lane] = zsq;          // r = lane for every i
    __syncthreads();

    u64 best[2][4];
#pragma unroll
    for (int rt = 0; rt < 2; ++rt)
#pragma unroll
        for (int reg = 0; reg < 4; ++reg) best[rt][reg] = ~0ull;

    for (int cb = 0; cb < 8; ++cb) {
        const int cBase = cb * 128;
        f32x4 acc[2][4];
#pragma unroll
        for (int rt = 0; rt < 2; ++rt)
#pragma unroll
            for (int ct = 0; ct < 4; ++ct) acc[rt][ct] = (f32x4){0.f, 0.f, 0.f, 0.f};

#pragma unroll
        for (int ks = 0; ks < 8; ++ks) {
            bf16x8 bfh[4], bfl[4];
            const size_t bbase = ((size_t)(ks * 4 + q) * 1024 + cBase + wcol * 64 + n16) * 8;
#pragma unroll
            for (int ct = 0; ct < 4; ++ct) {
                bfh[ct] = *(const bf16x8*)(Eph + bbase + ct * 128);
                bfl[ct] = *(const bf16x8*)(Epl + bbase + ct * 128);
            }
            bf16x8 afh[2], afl[2];
#pragma unroll
            for (int rt = 0; rt < 2; ++rt) {
                int ao = ((ks * 4 + q) * 64 + wrow * 32 + rt * 16 + n16) * 8;
                afh[rt] = *(const bf16x8*)&Ah[ao];
                afl[rt] = *(const bf16x8*)&Al[ao];
            }
#pragma unroll
            for (int rt = 0; rt < 2; ++rt)
#pragma unroll
                for (int ct = 0; ct < 4; ++ct) {
                    acc[rt][ct] = __builtin_amdgcn_mfma_f32_16x16x32_bf16(afh[rt], bfh[ct], acc[rt][ct], 0, 0, 0);
                    acc[rt][ct] = __builtin_amdgcn_mfma_f32_16x16x32_bf16(afh[rt], bfl[ct], acc[rt][ct], 0, 0, 0);
                    acc[rt][ct] = __builtin_amdgcn_mfma_f32_16x16x32_bf16(afl[rt], bfh[ct], acc[rt][ct], 0, 0, 0);
                }
        }

        // lane-local argmin update (no cross-lane work inside the cb loop)
        float cn[4];
#pragma unroll
        for (int ct = 0; ct < 4; ++ct) cn[ct] = colnorm[cBase + wcol * 64 + ct * 16 + n16];
#pragma unroll
        for (int rt = 0; rt < 2; ++rt)
#pragma unroll
            for (int reg = 0; reg < 4; ++reg) {
                u64 b = best[rt][reg];
#pragma unroll
                for (int ct = 0; ct < 4; ++ct) {
                    float dist = cn[ct] - 2.f * acc[rt][ct][reg];
                    unsigned fb = __float_as_uint(dist);
                    unsigned sk = (fb & 0x80000000u) ? ~fb : (fb | 0x80000000u);
                    unsigned code = (unsigned)(cBase + wcol * 64 + ct * 16 + n16);
                    b = umin64(b, ((u64)sk << 32) | code);
                }
                best[rt][reg] = b;
            }
    }

    // one-time cross-lane reduction within each 16-lane col group
#pragma unroll
    for (int rt = 0; rt < 2; ++rt)
#pragma unroll
        for (int reg = 0; reg < 4; ++reg) {
            u64 b = best[rt][reg];
            b = umin64(b, __shfl_xor(b, 1, 64));
            b = umin64(b, __shfl_xor(b, 2, 64));
            b = umin64(b, __shfl_xor(b, 4, 64));
            b = umin64(b, __shfl_xor(b, 8, 64));
            best[rt][reg] = b;
        }
    if (n16 == 0) {
#pragma unroll
        for (int rt = 0; rt < 2; ++rt)
#pragma unroll
            for (int reg = 0; reg < 4; ++reg)
                bl[wcol][wrow * 32 + rt * 16 + q * 4 + reg] = best[rt][reg];
    }
    __syncthreads();

    // ---- epilogue: merge wcol halves, decode key -> code + loss, hist ----
    if (t < 64) {
        u64 b = umin64(bl[0][t], bl[1][t]);
        int k = (int)(unsigned)(b & 0xFFFFFFFFull);
        unsigned sk = (unsigned)(b >> 32);
        unsigned fb = (sk & 0x80000000u) ? (sk ^ 0x80000000u) : ~sk;
        float zn = zpart[0][t] + zpart[1][t] + zpart[2][t] + zpart[3][t];
        float dmin = __uint_as_float(fb) + zn;
        idxOut[rowBase + t] = k;
        kArr[t] = k;
        atomicAdd(counts + k, 1);
        float v = dmin;
#pragma unroll
        for (int o = 32; o > 0; o >>= 1) v += __shfl_down(v, o, 64);
        if (t == 0) sred[0] = v;
    }
    __syncthreads();
    if (t == 0) atomicAdd(lossSum, sred[0]);

    // ---- gather z_q: wave w writes rows w*16..w*16+15 (no z re-read) ----
#pragma unroll
    for (int i = 0; i < 16; ++i) {
        int r = w * 16 + i;
        int k = kArr[r];
        float4 qv = *(const float4*)(ET + (size_t)k * 256 + lane * 4);
        *(float4*)(out0 + (size_t)(rowBase + r) * 256 + lane * 4) = qv;
    }
}

// ---------------- prefix scan + cluster_size_new + n + loss finalize ----------------
__global__ __launch_bounds__(1024) void prefix_csn_kernel(const int* __restrict__ counts,
                                                          const float* __restrict__ cluster_size,
                                                          const float* __restrict__ lossSum,
                                                          int* __restrict__ offsets,
                                                          int* __restrict__ cursor,
                                                          float* __restrict__ out3,
                                                          float* __restrict__ out1,
                                                          float* __restrict__ nOut) {
    __shared__ int sbuf[1024];
    int t = threadIdx.x;
    int c = counts[t];
    sbuf[t] = c;
    __syncthreads();
    for (int off = 1; off < 1024; off <<= 1) {
        int v = (t >= off) ? sbuf[t - off] : 0;
        __syncthreads();
        sbuf[t] += v;
        __syncthreads();
    }
    offsets[t] = sbuf[t] - c;
    if (t == 1023) offsets[1024] = sbuf[1023];
    cursor[t] = 0;

    float cn = cluster_size[t] * DECAYC + (1.f - DECAYC) * (float)c;
    out3[t] = cn;
    float v = cn;
#pragma unroll
    for (int o = 32; o > 0; o >>= 1) v += __shfl_down(v, o, 64);
    __shared__ float fbuf[16];
    int lane = t & 63, wv = t >> 6;
    if (lane == 0) fbuf[wv] = v;
    __syncthreads();
    if (t == 0) {
        float n = 0.f;
#pragma unroll
        for (int i = 0; i < 16; ++i) n += fbuf[i];
        nOut[0] = n;
        out1[0] = 0.25f * lossSum[0] / 16777216.0f;
    }
}

// ---------------- scatter row ids into code-sorted order ----------------
__global__ __launch_bounds__(256) void scatter_sort_kernel(const int* __restrict__ idx,
                                                           const int* __restrict__ offsets,
                                                           int* __restrict__ cursor,
                                                           int* __restrict__ sorted) {
    int i = blockIdx.x * 256 + threadIdx.x;
    int k = idx[i];
    int pos = atomicAdd(cursor + k, 1);
    sorted[offsets[k] + pos] = i;
}

// ---------------- sorted-gather segsum + embedding_mean_new + embedding_new ----------------
// Round-13 tail: replaces round-5's scan-based segsum_final (189us: every block
// re-scanned all 65536 idx with 8 barriers, then a serial 4B-load chain).
// Fine-grained sorted gather: grid 2048 = (code k, dim-half). 256 thr = 8
// row-slices x 32 float4-dim-groups. Each thread: ~8 independent float4 loads
// (avg 64 rows/code / 8 slices), fully coalesced per row. Tiny LDS/VGPR ->
// ~8 blocks/CU resident = deep TLP. Final EMA + normalize fused (no psum).
__global__ __launch_bounds__(256) void segsum_final_kernel(const float* __restrict__ z,
                                                           const int* __restrict__ sorted,
                                                           const int* __restrict__ offsets,
                                                           const float* __restrict__ embedding_mean,
                                                           const float* __restrict__ csn,
                                                           const float* __restrict__ nPtr,
                                                           float* __restrict__ out2,
                                                           float* __restrict__ out4) {
    const int k = blockIdx.x >> 1;
    const int half = blockIdx.x & 1;
    const int t = threadIdx.x;
    const int d4 = t & 31;           // float4 group within the 128-dim half
    const int slice = t >> 5;        // 0..7 row slice
    const int start = offsets[k], end = offsets[k + 1];
    float4 acc = {0.f, 0.f, 0.f, 0.f};
    const float* zh = z + half * 128 + d4 * 4;
    for (int j = start + slice; j < end; j += 8) {
        int row = sorted[j];
        float4 v = *(const float4*)(zh + (size_t)row * 256);
        acc.x += v.x; acc.y += v.y; acc.z += v.z; acc.w += v.w;
    }
    __shared__ float red[8][128];
    *(float4*)&red[slice][d4 * 4] = acc;
    __syncthreads();
    if (t < 32) {
        float4 s = *(const float4*)&red[0][t * 4];
#pragma unroll
        for (int sl = 1; sl < 8; ++sl) {
            float4 v = *(const float4*)&red[sl][t * 4];
            s.x += v.x; s.y += v.y; s.z += v.z; s.w += v.w;
        }
        float n = nPtr[0];
        float c = csn[k];
        float cs = (c + EPSQ) / (n + 1024.f * EPSQ) * n;
        float sv[4] = {s.x, s.y, s.z, s.w};
#pragma unroll
        for (int jj = 0; jj < 4; ++jj) {
            int D = half * 128 + t * 4 + jj;
            float emn = embedding_mean[(size_t)D * 1024 + k] * DECAYC + (1.f - DECAYC) * sv[jj];
            out4[(size_t)D * 1024 + k] = emn;
            out2[(size_t)D * 1024 + k] = emn / cs;
        }
    }
}

extern "C" void kernel_launch(void* const* d_in, const int* in_sizes, int n_in,
                              void* d_out, int out_size, void* d_ws, size_t ws_size,
                              hipStream_t stream) {
    const float* z = (const float*)d_in[0];
    const float* E = (const float*)d_in[1];
    const float* cluster_size = (const float*)d_in[2];
    const float* embedding_mean = (const float*)d_in[3];

    float* out0 = (float*)d_out;        // z_q_st
    float* out1 = out0 + 16777216;      // vq_loss
    float* out2 = out1 + 1;             // embedding_new
    float* out3 = out2 + 262144;        // cluster_size_new
    float* out4 = out3 + 1024;          // embedding_mean_new

    // ws layout (float units)
    float* ws = (float*)d_ws;
    float* colnorm = ws;                         // 1024
    int* idx = (int*)(ws + 1024);                // 65536
    int* counts = (int*)(ws + 66560);            // 1024  (zeroed in prep_E)
    float* lossSum = ws + 67584;                 // 1     (zeroed in prep_E)
    float* nOut = ws + 67585;                    // 1
    float* ET = ws + 67588;                      // 262144 fp32 [k][d]
    ushort_t* Eph = (ushort_t*)(ws + 329732);    // 262144 ushort
    ushort_t* Epl = (ushort_t*)(ws + 460804);    // 262144 ushort
    int* sorted = (int*)(ws + 2689028);          // 65536
    int* offsets = (int*)(ws + 2754564);         // 1025
    int* cursor = (int*)(ws + 2755592);          // 1024

    prep_E_kernel<<<1024, 256, 0, stream>>>(E, ET, colnorm, Eph, Epl, counts, lossSum);
    dist_mfma_kernel<<<1024, 256, 0, stream>>>(z, Eph, Epl, colnorm, ET,
                                               out0, lossSum, counts, idx);
    prefix_csn_kernel<<<1, 1024, 0, stream>>>(counts, cluster_size, lossSum,
                                              offsets, cursor, out3, out1, nOut);
    scatter_sort_kernel<<<256, 256, 0, stream>>>(idx, offsets, cursor, sorted);
    segsum_final_kernel<<<2048, 256, 0, stream>>>(z, sorted, offsets, embedding_mean,
                                                  out3, nOut, out2, out4);
}

// Round 7
// 299.040 us; speedup vs baseline: 1.4675x; 1.4120x over previous
//
#include <hip/hip_runtime.h>

// z: [16,4096,256] fp32 -> N=65536 rows, d=256
// embedding: [256,1024], cluster_size: [1024], embedding_mean: [256,1024]

#define DECAYC 0.99f
#define EPSQ 1e-5f

typedef unsigned short ushort_t;
typedef __attribute__((ext_vector_type(8))) short bf16x8;
typedef __attribute__((ext_vector_type(4))) float f32x4;
typedef unsigned long long u64;

__device__ __forceinline__ ushort_t f2bf(float x) {
    unsigned u = __float_as_uint(x);
    unsigned r = (u + 0x7FFFu + ((u >> 16) & 1u)) >> 16;   // RNE
    return (ushort_t)r;
}
__device__ __forceinline__ float bf2f(ushort_t h) {
    return __uint_as_float(((unsigned)h) << 16);
}
__device__ __forceinline__ u64 umin64(u64 a, u64 b) { return a < b ? a : b; }

// ---------------- E-side prep (fused): ET + colnorm + Eph/Epl + zero stats/psum ----------------
__global__ __launch_bounds__(256) void prep_E_kernel(const float* __restrict__ E,
                                                     float* __restrict__ ET,
                                                     float* __restrict__ colnorm,
                                                     ushort_t* __restrict__ Eph,
                                                     ushort_t* __restrict__ Epl,
                                                     int* __restrict__ counts,
                                                     float* __restrict__ lossSum,
                                                     float* __restrict__ psum) {
    int n = blockIdx.x;
    int d = threadIdx.x;
    if (d == 0) counts[n] = 0;
    if (n == 0 && d == 1) lossSum[0] = 0.f;
    psum[n * 256 + d] = 0.f;
    float v = E[d * 1024 + n];
    ET[n * 256 + d] = v;
    ushort_t h = f2bf(v);
    ushort_t l = f2bf(v - bf2f(h));
    size_t pi = ((size_t)(d >> 3) * 1024 + n) * 8 + (d & 7);
    Eph[pi] = h;
    Epl[pi] = l;
    __shared__ float red[256];
    red[d] = v * v;
    __syncthreads();
    for (int o = 128; o > 0; o >>= 1) {
        if (d < o) red[d] += red[d + o];
        __syncthreads();
    }
    if (d == 0) colnorm[n] = red[0];
}

// ---------------- MFMA distance + argmin + fused gather/loss/hist ----------------
// ROUND-0 VERBATIM (proven 142us, VGPR=128, no spill). Rounds 1-5 post-mortems:
// every attempt to beat this (32x32 shape, 4-wave occupancy, reg double-buffer)
// lost via the register/occupancy tradeoff.
__global__ __launch_bounds__(256, 2) void dist_mfma_kernel(const float* __restrict__ z,
                                                           const ushort_t* __restrict__ Eph,
                                                           const ushort_t* __restrict__ Epl,
                                                           const float* __restrict__ colnorm,
                                                           const float* __restrict__ ET,
                                                           float* __restrict__ out0,
                                                           float* __restrict__ lossSum,
                                                           int* __restrict__ counts,
                                                           int* __restrict__ idxOut) {
    __shared__ __align__(16) ushort_t Ah[16384];   // slots (kq*64+r)*8, 32 KB
    __shared__ __align__(16) ushort_t Al[16384];
    __shared__ u64 bl[2][64];                      // per-wcol row minima
    __shared__ float zpart[4][64];                 // per-wave ||z||^2 partials
    __shared__ int kArr[64];
    __shared__ float sred[1];

    const int t = threadIdx.x;
    const int lane = t & 63;
    const int w = t >> 6;          // wave 0..3
    const int wrow = w >> 1;       // 0..1 (rows wrow*32..)
    const int wcol = w & 1;        // 0..1 (codes wcol*64.. within chunk)
    const int n16 = lane & 15;
    const int q = lane >> 4;       // 0..3
    const int rowBase = blockIdx.x * 64;

    // ---- one-time: convert 64 z rows to bf16 hi/lo in LDS + ||z||^2 partials ----
    float zsq = 0.f;
#pragma unroll
    for (int i = 0; i < 8; ++i) {
        int s = i * 256 + t;       // slot: kq = s>>6, r = s&63
        int kq = s >> 6;
        int r = s & 63;
        const float* gp = z + (size_t)(rowBase + r) * 256 + kq * 8;
        float4 v0 = *(const float4*)gp;
        float4 v1 = *(const float4*)(gp + 4);
        float vv[8] = {v0.x, v0.y, v0.z, v0.w, v1.x, v1.y, v1.z, v1.w};
        ushort_t hh[8], ll[8];
#pragma unroll
        for (int j = 0; j < 8; ++j) {
            hh[j] = f2bf(vv[j]);
            ll[j] = f2bf(vv[j] - bf2f(hh[j]));
            zsq += vv[j] * vv[j];
        }
        ushort4 h0 = {hh[0], hh[1], hh[2], hh[3]}, h1 = {hh[4], hh[5], hh[6], hh[7]};
        ushort4 l0 = {ll[0], ll[1], ll[2], ll[3]}, l1 = {ll[4], ll[5], ll[6], ll[7]};
        *(ushort4*)&Ah[s * 8] = h0;
        *(ushort4*)&Ah[s * 8 + 4] = h1;
        *(ushort4*)&Al[s * 8] = l0;
        *(ushort4*)&Al[s * 8 + 4] = l1;
    }
    zpart[w][lane] = zsq;          // r = lane for every i
    __syncthreads();

    u64 best[2][4];
#pragma unroll
    for (int rt = 0; rt < 2; ++rt)
#pragma unroll
        for (int reg = 0; reg < 4; ++reg) best[rt][reg] = ~0ull;

    for (int cb = 0; cb < 8; ++cb) {
        const int cBase = cb * 128;
        f32x4 acc[2][4];
#pragma unroll
        for (int rt = 0; rt < 2; ++rt)
#pragma unroll
            for (int ct = 0; ct < 4; ++ct) acc[rt][ct] = (f32x4){0.f, 0.f, 0.f, 0.f};

#pragma unroll
        for (int ks = 0; ks < 8; ++ks) {
            bf16x8 bfh[4], bfl[4];
            const size_t bbase = ((size_t)(ks * 4 + q) * 1024 + cBase + wcol * 64 + n16) * 8;
#pragma unroll
            for (int ct = 0; ct < 4; ++ct) {
                bfh[ct] = *(const bf16x8*)(Eph + bbase + ct * 128);
                bfl[ct] = *(const bf16x8*)(Epl + bbase + ct * 128);
            }
            bf16x8 afh[2], afl[2];
#pragma unroll
            for (int rt = 0; rt < 2; ++rt) {
                int ao = ((ks * 4 + q) * 64 + wrow * 32 + rt * 16 + n16) * 8;
                afh[rt] = *(const bf16x8*)&Ah[ao];
                afl[rt] = *(const bf16x8*)&Al[ao];
            }
#pragma unroll
            for (int rt = 0; rt < 2; ++rt)
#pragma unroll
                for (int ct = 0; ct < 4; ++ct) {
                    acc[rt][ct] = __builtin_amdgcn_mfma_f32_16x16x32_bf16(afh[rt], bfh[ct], acc[rt][ct], 0, 0, 0);
                    acc[rt][ct] = __builtin_amdgcn_mfma_f32_16x16x32_bf16(afh[rt], bfl[ct], acc[rt][ct], 0, 0, 0);
                    acc[rt][ct] = __builtin_amdgcn_mfma_f32_16x16x32_bf16(afl[rt], bfh[ct], acc[rt][ct], 0, 0, 0);
                }
        }

        // lane-local argmin update (no cross-lane work inside the cb loop)
        float cn[4];
#pragma unroll
        for (int ct = 0; ct < 4; ++ct) cn[ct] = colnorm[cBase + wcol * 64 + ct * 16 + n16];
#pragma unroll
        for (int rt = 0; rt < 2; ++rt)
#pragma unroll
            for (int reg = 0; reg < 4; ++reg) {
                u64 b = best[rt][reg];
#pragma unroll
                for (int ct = 0; ct < 4; ++ct) {
                    float dist = cn[ct] - 2.f * acc[rt][ct][reg];
                    unsigned fb = __float_as_uint(dist);
                    unsigned sk = (fb & 0x80000000u) ? ~fb : (fb | 0x80000000u);
                    unsigned code = (unsigned)(cBase + wcol * 64 + ct * 16 + n16);
                    b = umin64(b, ((u64)sk << 32) | code);
                }
                best[rt][reg] = b;
            }
    }

    // one-time cross-lane reduction within each 16-lane col group
#pragma unroll
    for (int rt = 0; rt < 2; ++rt)
#pragma unroll
        for (int reg = 0; reg < 4; ++reg) {
            u64 b = best[rt][reg];
            b = umin64(b, __shfl_xor(b, 1, 64));
            b = umin64(b, __shfl_xor(b, 2, 64));
            b = umin64(b, __shfl_xor(b, 4, 64));
            b = umin64(b, __shfl_xor(b, 8, 64));
            best[rt][reg] = b;
        }
    if (n16 == 0) {
#pragma unroll
        for (int rt = 0; rt < 2; ++rt)
#pragma unroll
            for (int reg = 0; reg < 4; ++reg)
                bl[wcol][wrow * 32 + rt * 16 + q * 4 + reg] = best[rt][reg];
    }
    __syncthreads();

    // ---- epilogue: merge wcol halves, decode key -> code + loss, hist ----
    if (t < 64) {
        u64 b = umin64(bl[0][t], bl[1][t]);
        int k = (int)(unsigned)(b & 0xFFFFFFFFull);
        unsigned sk = (unsigned)(b >> 32);
        unsigned fb = (sk & 0x80000000u) ? (sk ^ 0x80000000u) : ~sk;
        float zn = zpart[0][t] + zpart[1][t] + zpart[2][t] + zpart[3][t];
        float dmin = __uint_as_float(fb) + zn;
        idxOut[rowBase + t] = k;
        kArr[t] = k;
        atomicAdd(counts + k, 1);
        float v = dmin;
#pragma unroll
        for (int o = 32; o > 0; o >>= 1) v += __shfl_down(v, o, 64);
        if (t == 0) sred[0] = v;
    }
    __syncthreads();
    if (t == 0) atomicAdd(lossSum, sred[0]);

    // ---- gather z_q: wave w writes rows w*16..w*16+15 (no z re-read) ----
#pragma unroll
    for (int i = 0; i < 16; ++i) {
        int r = w * 16 + i;
        int k = kArr[r];
        float4 qv = *(const float4*)(ET + (size_t)k * 256 + lane * 4);
        *(float4*)(out0 + (size_t)(rowBase + r) * 256 + lane * 4) = qv;
    }
}

// ---------------- prefix scan + cluster_size_new + n + loss finalize ----------------
__global__ __launch_bounds__(1024) void prefix_csn_kernel(const int* __restrict__ counts,
                                                          const float* __restrict__ cluster_size,
                                                          const float* __restrict__ lossSum,
                                                          int* __restrict__ offsets,
                                                          int* __restrict__ cursor,
                                                          float* __restrict__ out3,
                                                          float* __restrict__ out1,
                                                          float* __restrict__ nOut) {
    __shared__ int sbuf[1024];
    int t = threadIdx.x;
    int c = counts[t];
    sbuf[t] = c;
    __syncthreads();
    for (int off = 1; off < 1024; off <<= 1) {
        int v = (t >= off) ? sbuf[t - off] : 0;
        __syncthreads();
        sbuf[t] += v;
        __syncthreads();
    }
    offsets[t] = sbuf[t] - c;
    if (t == 1023) offsets[1024] = sbuf[1023];
    cursor[t] = 0;

    float cn = cluster_size[t] * DECAYC + (1.f - DECAYC) * (float)c;
    out3[t] = cn;
    float v = cn;
#pragma unroll
    for (int o = 32; o > 0; o >>= 1) v += __shfl_down(v, o, 64);
    __shared__ float fbuf[16];
    int lane = t & 63, wv = t >> 6;
    if (lane == 0) fbuf[wv] = v;
    __syncthreads();
    if (t == 0) {
        float n = 0.f;
#pragma unroll
        for (int i = 0; i < 16; ++i) n += fbuf[i];
        nOut[0] = n;
        out1[0] = 0.25f * lossSum[0] / 16777216.0f;
    }
}

// ---------------- scatter row ids into code-sorted order ----------------
__global__ __launch_bounds__(256) void scatter_sort_kernel(const int* __restrict__ idx,
                                                           const int* __restrict__ offsets,
                                                           int* __restrict__ cursor,
                                                           int* __restrict__ sorted) {
    int i = blockIdx.x * 256 + threadIdx.x;
    int k = idx[i];
    int pos = atomicAdd(cursor + k, 1);
    sorted[offsets[k] + pos] = i;
}

// ---------------- balanced chunked segsum (atomic flush on code boundary) ----------------
// Round-14 tail fix. Round-6 post-mortem: per-code blocks -> skewed clusters ->
// straggler blocks, 4% occupancy, 160us. This version: uniform partition of the
// sorted array; each wave owns EXACTLY 32 consecutive sorted entries (perfect
// balance regardless of cluster skew). Lanes prefetch the 32 row-ids + codes up
// front (batch load + __shfl broadcast -> no per-iteration dependent idx load).
// Per entry: all 64 lanes load the row's float4 (1KB contiguous, coalesced),
// accumulate; on wave-uniform code-boundary flush atomicAdd into psum[k][d]
// (~3K flushes total, L2-resident 1MB target).
__global__ __launch_bounds__(256) void segsum_atomic_kernel(const float* __restrict__ z,
                                                            const int* __restrict__ sorted,
                                                            const int* __restrict__ idx,
                                                            float* __restrict__ psum) {
    const int t = threadIdx.x;
    const int lane = t & 63;
    const int w = t >> 6;
    const int j0 = (blockIdx.x * 4 + w) * 32;
    const int row_v = sorted[j0 + (lane & 31)];
    const int k_v = idx[row_v];
    float4 acc = {0.f, 0.f, 0.f, 0.f};
    int kcur = __shfl(k_v, 0, 64);
#pragma unroll 4
    for (int i = 0; i < 32; ++i) {
        int row = __shfl(row_v, i, 64);
        int k = __shfl(k_v, i, 64);
        if (k != kcur) {                       // wave-uniform branch
            float* p = psum + (size_t)kcur * 256 + lane * 4;
            atomicAdd(p + 0, acc.x);
            atomicAdd(p + 1, acc.y);
            atomicAdd(p + 2, acc.z);
            atomicAdd(p + 3, acc.w);
            acc = (float4){0.f, 0.f, 0.f, 0.f};
            kcur = k;
        }
        float4 v = *(const float4*)(z + (size_t)row * 256 + lane * 4);
        acc.x += v.x; acc.y += v.y; acc.z += v.z; acc.w += v.w;
    }
    float* p = psum + (size_t)kcur * 256 + lane * 4;
    atomicAdd(p + 0, acc.x);
    atomicAdd(p + 1, acc.y);
    atomicAdd(p + 2, acc.z);
    atomicAdd(p + 3, acc.w);
}

// ---------------- embedding_mean_new + embedding_new from psum ----------------
__global__ __launch_bounds__(256) void finalE_kernel(const float* __restrict__ embedding_mean,
                                                     const float* __restrict__ psum,
                                                     const float* __restrict__ csn,
                                                     const float* __restrict__ nPtr,
                                                     float* __restrict__ out2,
                                                     float* __restrict__ out4) {
    int tid = blockIdx.x * 256 + threadIdx.x;
    int d = tid >> 10;
    int k = tid & 1023;
    float es = psum[(size_t)k * 256 + d];      // uncoalesced but L2-resident (1MB)
    float emn = embedding_mean[tid] * DECAYC + (1.f - DECAYC) * es;
    out4[tid] = emn;
    float n = nPtr[0];
    float c = csn[k];
    float cs = (c + EPSQ) / (n + 1024.f * EPSQ) * n;
    out2[tid] = emn / cs;
}

extern "C" void kernel_launch(void* const* d_in, const int* in_sizes, int n_in,
                              void* d_out, int out_size, void* d_ws, size_t ws_size,
                              hipStream_t stream) {
    const float* z = (const float*)d_in[0];
    const float* E = (const float*)d_in[1];
    const float* cluster_size = (const float*)d_in[2];
    const float* embedding_mean = (const float*)d_in[3];

    float* out0 = (float*)d_out;        // z_q_st
    float* out1 = out0 + 16777216;      // vq_loss
    float* out2 = out1 + 1;             // embedding_new
    float* out3 = out2 + 262144;        // cluster_size_new
    float* out4 = out3 + 1024;          // embedding_mean_new

    // ws layout (float units)
    float* ws = (float*)d_ws;
    float* colnorm = ws;                         // 1024
    int* idx = (int*)(ws + 1024);                // 65536
    int* counts = (int*)(ws + 66560);            // 1024  (zeroed in prep_E)
    float* lossSum = ws + 67584;                 // 1     (zeroed in prep_E)
    float* nOut = ws + 67585;                    // 1
    float* ET = ws + 67588;                      // 262144 fp32 [k][d]
    ushort_t* Eph = (ushort_t*)(ws + 329732);    // 262144 ushort
    ushort_t* Epl = (ushort_t*)(ws + 460804);    // 262144 ushort
    float* psum = ws + 591876;                   // 262144 [k][d] (zeroed in prep_E)
    int* sorted = (int*)(ws + 2689028);          // 65536
    int* offsets = (int*)(ws + 2754564);         // 1025
    int* cursor = (int*)(ws + 2755592);          // 1024

    prep_E_kernel<<<1024, 256, 0, stream>>>(E, ET, colnorm, Eph, Epl, counts, lossSum, psum);
    dist_mfma_kernel<<<1024, 256, 0, stream>>>(z, Eph, Epl, colnorm, ET,
                                               out0, lossSum, counts, idx);
    prefix_csn_kernel<<<1, 1024, 0, stream>>>(counts, cluster_size, lossSum,
                                              offsets, cursor, out3, out1, nOut);
    scatter_sort_kernel<<<256, 256, 0, stream>>>(idx, offsets, cursor, sorted);
    segsum_atomic_kernel<<<512, 256, 0, stream>>>(z, sorted, idx, psum);
    finalE_kernel<<<1024, 256, 0, stream>>>(embedding_mean, psum, out3, nOut, out2, out4);
}